// Round 1
// baseline (7978.059 us; speedup 1.0000x reference)
//
#include <hip/hip_runtime.h>
#include <hip/hip_bf16.h>

#define N_NODES 100000
#define N_EDGES 1600000
#define IN_FEAT 64
#define OUT_FEAT 64
#define NUM_RELS 8

// ---------------------------------------------------------------------------
// K1: transformed[r][n][o] = sum_i feat[n][i] * W[r][i][o]
// One block per 64-node tile; loops over all 8 relations reusing the staged
// feat tile. W[r] (16KB) staged in LDS per relation; feat tile staged
// TRANSPOSED (Ft[i][n], stride 68 to break bank conflicts) so the inner loop
// does broadcast b128 reads (4 node-values) + one conflict-free W read per
// 16 lane-FMAs. Stores are fully coalesced (o = lane).
// ---------------------------------------------------------------------------
__global__ __launch_bounds__(256) void k_transform(const float* __restrict__ feat,
                                                   const float* __restrict__ W,
                                                   float* __restrict__ tr) {
    __shared__ float Wl[64 * 64];    // Wl[i*64 + o]
    __shared__ float Ft[64 * 68];    // Ft[i*68 + n], padded stride
    const int tid = threadIdx.x;
    const int n0 = blockIdx.x * 64;

    // Stage feat tile (transposed). 256 threads x 4 iters x float4 = 16KB.
    #pragma unroll
    for (int it = 0; it < 4; ++it) {
        int m = it * 256 + tid;
        int n = m >> 4;          // node within tile [0,64)
        int c4 = m & 15;         // which float4 of the row
        int gn = n0 + n;
        float4 v = make_float4(0.f, 0.f, 0.f, 0.f);
        if (gn < N_NODES) v = *(const float4*)(feat + (size_t)gn * IN_FEAT + c4 * 4);
        Ft[(c4 * 4 + 0) * 68 + n] = v.x;
        Ft[(c4 * 4 + 1) * 68 + n] = v.y;
        Ft[(c4 * 4 + 2) * 68 + n] = v.z;
        Ft[(c4 * 4 + 3) * 68 + n] = v.w;
    }

    const int o  = tid & 63;     // output column = lane
    const int ng = tid >> 6;     // node sub-group (16 nodes per wave)

    for (int rel = 0; rel < NUM_RELS; ++rel) {
        __syncthreads();   // protect Wl (and Ft on first iter) before overwrite
        {
            const float4* Wg = (const float4*)(W + (size_t)rel * 4096);
            float4* Wl4 = (float4*)Wl;
            #pragma unroll
            for (int it = 0; it < 4; ++it) Wl4[it * 256 + tid] = Wg[it * 256 + tid];
        }
        __syncthreads();

        float acc[16];
        #pragma unroll
        for (int j = 0; j < 16; ++j) acc[j] = 0.f;

        #pragma unroll
        for (int i = 0; i < 64; ++i) {
            float w = Wl[i * 64 + o];                       // conflict-free (2 lanes/bank)
            const float4* fp = (const float4*)(Ft + i * 68 + ng * 16);  // wave-broadcast
            #pragma unroll
            for (int g = 0; g < 4; ++g) {
                float4 f = fp[g];
                acc[g * 4 + 0] += f.x * w;
                acc[g * 4 + 1] += f.y * w;
                acc[g * 4 + 2] += f.z * w;
                acc[g * 4 + 3] += f.w * w;
            }
        }

        // Store: tr[rel][n0 + ng*16 + nn][o] — 256B coalesced per wave-store.
        float* trp = tr + ((size_t)rel * N_NODES + n0 + ng * 16) * OUT_FEAT + o;
        #pragma unroll
        for (int nn = 0; nn < 16; ++nn) {
            int gn = n0 + ng * 16 + nn;
            if (gn < N_NODES) trp[(size_t)nn * OUT_FEAT] = acc[nn];
        }
    }
}

// ---------------------------------------------------------------------------
// K2: per-edge gather + scale + atomic scatter.
// 16 threads per edge, each handling a float4 (coalesced 256B row reads).
// ---------------------------------------------------------------------------
__global__ __launch_bounds__(256) void k_scatter(const float* __restrict__ tr,
                                                 const float* __restrict__ norm,
                                                 const int* __restrict__ etypes,
                                                 const int* __restrict__ src,
                                                 const int* __restrict__ dst,
                                                 float* __restrict__ out) {
    int gid = blockIdx.x * 256 + threadIdx.x;
    int e = gid >> 4;
    int q = gid & 15;
    if (e >= N_EDGES) return;
    int et = etypes[e];
    int s  = src[e];
    int d  = dst[e];
    float nv = norm[e];
    float4 v = *(const float4*)(tr + ((size_t)et * N_NODES + s) * OUT_FEAT + q * 4);
    float* op = out + (size_t)d * OUT_FEAT + q * 4;
    atomicAdd(op + 0, v.x * nv);
    atomicAdd(op + 1, v.y * nv);
    atomicAdd(op + 2, v.z * nv);
    atomicAdd(op + 3, v.w * nv);
}

// ---------------------------------------------------------------------------
// Fallback (ws too small): direct per-edge matvec + atomic scatter.
// 16 threads per edge; W rows read from L1/L2 (128KB total, hot).
// ---------------------------------------------------------------------------
__global__ __launch_bounds__(256) void k_direct(const float* __restrict__ feat,
                                                const float* __restrict__ W,
                                                const float* __restrict__ norm,
                                                const int* __restrict__ etypes,
                                                const int* __restrict__ src,
                                                const int* __restrict__ dst,
                                                float* __restrict__ out) {
    int gid = blockIdx.x * 256 + threadIdx.x;
    int e = gid >> 4;
    int q = gid & 15;
    if (e >= N_EDGES) return;
    int et = etypes[e];
    int s  = src[e];
    int d  = dst[e];
    float nv = norm[e];
    const float* fs = feat + (size_t)s * IN_FEAT;
    const float* wp = W + (size_t)et * 4096 + q * 4;
    float ax = 0.f, ay = 0.f, az = 0.f, aw = 0.f;
    #pragma unroll 8
    for (int i = 0; i < IN_FEAT; ++i) {
        float f = fs[i];
        float4 w = *(const float4*)(wp + i * OUT_FEAT);
        ax += f * w.x; ay += f * w.y; az += f * w.z; aw += f * w.w;
    }
    float* op = out + (size_t)d * OUT_FEAT + q * 4;
    atomicAdd(op + 0, ax * nv);
    atomicAdd(op + 1, ay * nv);
    atomicAdd(op + 2, az * nv);
    atomicAdd(op + 3, aw * nv);
}

extern "C" void kernel_launch(void* const* d_in, const int* in_sizes, int n_in,
                              void* d_out, int out_size, void* d_ws, size_t ws_size,
                              hipStream_t stream) {
    const float* feat   = (const float*)d_in[0];
    const float* norm   = (const float*)d_in[1];
    const float* W      = (const float*)d_in[2];
    const int*   etypes = (const int*)d_in[3];
    const int*   src    = (const int*)d_in[4];
    const int*   dst    = (const int*)d_in[5];
    float* out = (float*)d_out;

    // We accumulate into out with atomics; harness does not re-zero between
    // timed replays, so zero it ourselves (async memset is graph-capturable).
    hipMemsetAsync(d_out, 0, (size_t)out_size * sizeof(float), stream);

    const size_t need = (size_t)NUM_RELS * N_NODES * OUT_FEAT * sizeof(float); // 204.8 MB
    const int ntiles = (N_NODES + 63) / 64;           // 1563
    const int nscat  = (N_EDGES * 16) / 256;          // 100000 blocks exactly

    if (ws_size >= need) {
        float* tr = (float*)d_ws;
        k_transform<<<ntiles, 256, 0, stream>>>(feat, W, tr);
        k_scatter<<<nscat, 256, 0, stream>>>(tr, norm, etypes, src, dst, out);
    } else {
        k_direct<<<nscat, 256, 0, stream>>>(feat, W, norm, etypes, src, dst, out);
    }
}

// Round 2
// 1457.930 us; speedup vs baseline: 5.4722x; 5.4722x over previous
//
#include <hip/hip_runtime.h>
#include <hip/hip_bf16.h>

#define N_NODES 100000
#define N_EDGES 1600000
#define IN_FEAT 64
#define OUT_FEAT 64
#define NUM_RELS 8

// ---------------------------------------------------------------------------
// K1: transformed[r][n][o] = sum_i feat[n][i] * W[r][i][o]
// Register-blocked GEMM. Block = 64-node x 64-output tile, looped over all 8
// relations (feat tile staged once, W[r] restaged per relation). Each thread
// computes a 4x4 micro-tile: per K-step it reads ONE float4 of transposed
// feat (Ft[i][n..n+4]) and ONE float4 of W (Wl[i][o..o+4]) from LDS -> 2
// ds_read_b128 per 16 FMAs (FMA-bound). Bounded unroll + launch_bounds cap
// VGPRs (round-1 version fully unrolled 64x16 FMAs -> 256 VGPR + scratch
// spill -> 11 GB HBM traffic, 6.7 ms).
// ---------------------------------------------------------------------------
__global__ __launch_bounds__(256, 4) void k_transform(const float* __restrict__ feat,
                                                      const float* __restrict__ W,
                                                      float* __restrict__ tr) {
    __shared__ float Wl[64 * 64];    // Wl[i*64 + o]
    __shared__ float Ft[64 * 68];    // Ft[i*68 + n]; stride 68 keeps float4 align (272B)
    const int tid = threadIdx.x;
    const int n0 = blockIdx.x * 64;

    // Stage feat tile transposed: 64 rows x 16 float4, 4 float4 per thread.
    #pragma unroll
    for (int it = 0; it < 4; ++it) {
        int m = it * 256 + tid;
        int n = m >> 4;          // node within tile [0,64)
        int c4 = m & 15;         // which float4 of the row
        int gn = n0 + n;
        float4 v = make_float4(0.f, 0.f, 0.f, 0.f);
        if (gn < N_NODES) v = *(const float4*)(feat + (size_t)gn * IN_FEAT + c4 * 4);
        Ft[(c4 * 4 + 0) * 68 + n] = v.x;
        Ft[(c4 * 4 + 1) * 68 + n] = v.y;
        Ft[(c4 * 4 + 2) * 68 + n] = v.z;
        Ft[(c4 * 4 + 3) * 68 + n] = v.w;
    }

    const int to = tid & 15;     // output quad  -> o in [to*4, to*4+4)
    const int tn = tid >> 4;     // node quad    -> n in [tn*4, tn*4+4)

    for (int rel = 0; rel < NUM_RELS; ++rel) {
        __syncthreads();   // protect Wl (and Ft on first iter) before overwrite
        {
            const float4* Wg = (const float4*)(W + (size_t)rel * 4096);
            float4* Wl4 = (float4*)Wl;
            #pragma unroll
            for (int it = 0; it < 4; ++it) Wl4[it * 256 + tid] = Wg[it * 256 + tid];
        }
        __syncthreads();

        float acc[16];
        #pragma unroll
        for (int j = 0; j < 16; ++j) acc[j] = 0.f;

        #pragma unroll 4
        for (int i = 0; i < 64; ++i) {
            float4 a = *(const float4*)(Ft + i * 68 + tn * 4);  // 4 addrs/wave, bcast
            float4 w = *(const float4*)(Wl + i * 64 + to * 4);  // 16 addrs, 2-way free
            acc[0]  += a.x * w.x; acc[1]  += a.x * w.y; acc[2]  += a.x * w.z; acc[3]  += a.x * w.w;
            acc[4]  += a.y * w.x; acc[5]  += a.y * w.y; acc[6]  += a.y * w.z; acc[7]  += a.y * w.w;
            acc[8]  += a.z * w.x; acc[9]  += a.z * w.y; acc[10] += a.z * w.z; acc[11] += a.z * w.w;
            acc[12] += a.w * w.x; acc[13] += a.w * w.y; acc[14] += a.w * w.z; acc[15] += a.w * w.w;
        }

        // Store 4x4 micro-tile: per (tn,p) row the 16 'to' lanes cover 256B.
        #pragma unroll
        for (int p = 0; p < 4; ++p) {
            int gn = n0 + tn * 4 + p;
            if (gn < N_NODES) {
                float4 v = make_float4(acc[p * 4 + 0], acc[p * 4 + 1],
                                       acc[p * 4 + 2], acc[p * 4 + 3]);
                *(float4*)(tr + ((size_t)rel * N_NODES + gn) * OUT_FEAT + to * 4) = v;
            }
        }
    }
}

// ---------------------------------------------------------------------------
// K2: per-edge gather + scale + atomic scatter.
// 16 threads per edge, each handling a float4 (coalesced 256B row reads).
// ---------------------------------------------------------------------------
__global__ __launch_bounds__(256) void k_scatter(const float* __restrict__ tr,
                                                 const float* __restrict__ norm,
                                                 const int* __restrict__ etypes,
                                                 const int* __restrict__ src,
                                                 const int* __restrict__ dst,
                                                 float* __restrict__ out) {
    int gid = blockIdx.x * 256 + threadIdx.x;
    int e = gid >> 4;
    int q = gid & 15;
    if (e >= N_EDGES) return;
    int et = etypes[e];
    int s  = src[e];
    int d  = dst[e];
    float nv = norm[e];
    float4 v = *(const float4*)(tr + ((size_t)et * N_NODES + s) * OUT_FEAT + q * 4);
    float* op = out + (size_t)d * OUT_FEAT + q * 4;
    atomicAdd(op + 0, v.x * nv);
    atomicAdd(op + 1, v.y * nv);
    atomicAdd(op + 2, v.z * nv);
    atomicAdd(op + 3, v.w * nv);
}

// ---------------------------------------------------------------------------
// Fallback (ws too small): direct per-edge matvec + atomic scatter.
// ---------------------------------------------------------------------------
__global__ __launch_bounds__(256) void k_direct(const float* __restrict__ feat,
                                                const float* __restrict__ W,
                                                const float* __restrict__ norm,
                                                const int* __restrict__ etypes,
                                                const int* __restrict__ src,
                                                const int* __restrict__ dst,
                                                float* __restrict__ out) {
    int gid = blockIdx.x * 256 + threadIdx.x;
    int e = gid >> 4;
    int q = gid & 15;
    if (e >= N_EDGES) return;
    int et = etypes[e];
    int s  = src[e];
    int d  = dst[e];
    float nv = norm[e];
    const float* fs = feat + (size_t)s * IN_FEAT;
    const float* wp = W + (size_t)et * 4096 + q * 4;
    float ax = 0.f, ay = 0.f, az = 0.f, aw = 0.f;
    #pragma unroll 8
    for (int i = 0; i < IN_FEAT; ++i) {
        float f = fs[i];
        float4 w = *(const float4*)(wp + i * OUT_FEAT);
        ax += f * w.x; ay += f * w.y; az += f * w.z; aw += f * w.w;
    }
    float* op = out + (size_t)d * OUT_FEAT + q * 4;
    atomicAdd(op + 0, ax * nv);
    atomicAdd(op + 1, ay * nv);
    atomicAdd(op + 2, az * nv);
    atomicAdd(op + 3, aw * nv);
}

extern "C" void kernel_launch(void* const* d_in, const int* in_sizes, int n_in,
                              void* d_out, int out_size, void* d_ws, size_t ws_size,
                              hipStream_t stream) {
    const float* feat   = (const float*)d_in[0];
    const float* norm   = (const float*)d_in[1];
    const float* W      = (const float*)d_in[2];
    const int*   etypes = (const int*)d_in[3];
    const int*   src    = (const int*)d_in[4];
    const int*   dst    = (const int*)d_in[5];
    float* out = (float*)d_out;

    // We accumulate into out with atomics; harness does not re-zero between
    // timed replays, so zero it ourselves (async memset is graph-capturable).
    hipMemsetAsync(d_out, 0, (size_t)out_size * sizeof(float), stream);

    const size_t need = (size_t)NUM_RELS * N_NODES * OUT_FEAT * sizeof(float); // 204.8 MB
    const int ntiles = (N_NODES + 63) / 64;           // 1563
    const int nscat  = (N_EDGES * 16) / 256;          // 100000 blocks exactly

    if (ws_size >= need) {
        float* tr = (float*)d_ws;
        k_transform<<<ntiles, 256, 0, stream>>>(feat, W, tr);
        k_scatter<<<nscat, 256, 0, stream>>>(tr, norm, etypes, src, dst, out);
    } else {
        k_direct<<<nscat, 256, 0, stream>>>(feat, W, norm, etypes, src, dst, out);
    }
}

// Round 3
// 337.236 us; speedup vs baseline: 23.6572x; 4.3232x over previous
//
#include <hip/hip_runtime.h>
#include <hip/hip_bf16.h>

#define N_NODES 100000
#define N_EDGES 1600000
#define IN_FEAT 64
#define OUT_FEAT 64
#define NUM_RELS 8

#define SCAN_ELEMS 1024                      // elements per scan block (256 thr x 4)
#define SCAN_NB ((N_NODES + SCAN_ELEMS - 1) / SCAN_ELEMS)   // 98

// ---------------------------------------------------------------------------
// K1: transformed[r][n][o] = sum_i feat[n][i] * W[r][i][o]
// Register-blocked GEMM, 4x4 micro-tile per thread (see round-2 notes: full
// unroll spilled at 256 VGPR; this shape is FMA-bound, ~100us).
// ---------------------------------------------------------------------------
__global__ __launch_bounds__(256, 4) void k_transform(const float* __restrict__ feat,
                                                      const float* __restrict__ W,
                                                      float* __restrict__ tr) {
    __shared__ float Wl[64 * 64];    // Wl[i*64 + o]
    __shared__ float Ft[64 * 68];    // Ft[i*68 + n]
    const int tid = threadIdx.x;
    const int n0 = blockIdx.x * 64;

    #pragma unroll
    for (int it = 0; it < 4; ++it) {
        int m = it * 256 + tid;
        int n = m >> 4;
        int c4 = m & 15;
        int gn = n0 + n;
        float4 v = make_float4(0.f, 0.f, 0.f, 0.f);
        if (gn < N_NODES) v = *(const float4*)(feat + (size_t)gn * IN_FEAT + c4 * 4);
        Ft[(c4 * 4 + 0) * 68 + n] = v.x;
        Ft[(c4 * 4 + 1) * 68 + n] = v.y;
        Ft[(c4 * 4 + 2) * 68 + n] = v.z;
        Ft[(c4 * 4 + 3) * 68 + n] = v.w;
    }

    const int to = tid & 15;
    const int tn = tid >> 4;

    for (int rel = 0; rel < NUM_RELS; ++rel) {
        __syncthreads();
        {
            const float4* Wg = (const float4*)(W + (size_t)rel * 4096);
            float4* Wl4 = (float4*)Wl;
            #pragma unroll
            for (int it = 0; it < 4; ++it) Wl4[it * 256 + tid] = Wg[it * 256 + tid];
        }
        __syncthreads();

        float acc[16];
        #pragma unroll
        for (int j = 0; j < 16; ++j) acc[j] = 0.f;

        #pragma unroll 4
        for (int i = 0; i < 64; ++i) {
            float4 a = *(const float4*)(Ft + i * 68 + tn * 4);
            float4 w = *(const float4*)(Wl + i * 64 + to * 4);
            acc[0]  += a.x * w.x; acc[1]  += a.x * w.y; acc[2]  += a.x * w.z; acc[3]  += a.x * w.w;
            acc[4]  += a.y * w.x; acc[5]  += a.y * w.y; acc[6]  += a.y * w.z; acc[7]  += a.y * w.w;
            acc[8]  += a.z * w.x; acc[9]  += a.z * w.y; acc[10] += a.z * w.z; acc[11] += a.z * w.w;
            acc[12] += a.w * w.x; acc[13] += a.w * w.y; acc[14] += a.w * w.z; acc[15] += a.w * w.w;
        }

        #pragma unroll
        for (int p = 0; p < 4; ++p) {
            int gn = n0 + tn * 4 + p;
            if (gn < N_NODES) {
                float4 v = make_float4(acc[p * 4 + 0], acc[p * 4 + 1],
                                       acc[p * 4 + 2], acc[p * 4 + 3]);
                *(float4*)(tr + ((size_t)rel * N_NODES + gn) * OUT_FEAT + to * 4) = v;
            }
        }
    }
}

// ---------------------------------------------------------------------------
// S1: histogram of dst. count[] pre-zeroed by memsetAsync.
// ---------------------------------------------------------------------------
__global__ __launch_bounds__(256) void k_hist(const int* __restrict__ dst,
                                              int* __restrict__ count) {
    int e = blockIdx.x * 256 + threadIdx.x;
    if (e < N_EDGES) atomicAdd(&count[dst[e]], 1);
}

// ---------------------------------------------------------------------------
// S2a: per-block (1024-elem) exclusive scan of count -> base (partial),
//      block totals -> bsum.
// ---------------------------------------------------------------------------
__global__ __launch_bounds__(256) void k_scan_local(const int* __restrict__ count,
                                                    int* __restrict__ base,
                                                    int* __restrict__ bsum) {
    __shared__ int sdata[256];
    const int b = blockIdx.x, t = threadIdx.x;
    const int idx0 = b * SCAN_ELEMS + t * 4;
    int v[4];
    #pragma unroll
    for (int k = 0; k < 4; ++k)
        v[k] = (idx0 + k < N_NODES) ? count[idx0 + k] : 0;
    int s = v[0] + v[1] + v[2] + v[3];
    sdata[t] = s;
    __syncthreads();
    // Hillis-Steele inclusive scan over 256 thread sums
    for (int off = 1; off < 256; off <<= 1) {
        int x = (t >= off) ? sdata[t - off] : 0;
        __syncthreads();
        sdata[t] += x;
        __syncthreads();
    }
    int excl = sdata[t] - s;   // exclusive prefix of this thread's 4 elems
    int run = excl;
    #pragma unroll
    for (int k = 0; k < 4; ++k) {
        if (idx0 + k < N_NODES) base[idx0 + k] = run;
        run += v[k];
    }
    if (t == 255) bsum[b] = sdata[255];
}

// ---------------------------------------------------------------------------
// S2b: serial exclusive scan of the 98 block sums (launch-latency bound).
// ---------------------------------------------------------------------------
__global__ void k_scan_blocks(const int* __restrict__ bsum, int* __restrict__ boff) {
    if (threadIdx.x == 0 && blockIdx.x == 0) {
        int run = 0;
        for (int i = 0; i < SCAN_NB; ++i) { boff[i] = run; run += bsum[i]; }
    }
}

// ---------------------------------------------------------------------------
// S2c: add block offsets; cursor <- base; base[N] = E.
// ---------------------------------------------------------------------------
__global__ __launch_bounds__(256) void k_scan_fix(int* __restrict__ base,
                                                  int* __restrict__ cursor,
                                                  const int* __restrict__ boff) {
    const int b = blockIdx.x, t = threadIdx.x;
    const int off = boff[b];
    const int idx0 = b * SCAN_ELEMS + t * 4;
    #pragma unroll
    for (int k = 0; k < 4; ++k) {
        int i = idx0 + k;
        if (i < N_NODES) {
            int v = base[i] + off;
            base[i] = v;
            cursor[i] = v;
        }
    }
    if (b == 0 && t == 0) base[N_NODES] = N_EDGES;
}

// ---------------------------------------------------------------------------
// S3: permute edges into dst-sorted order. payload = {rowid, norm bits}.
// ---------------------------------------------------------------------------
__global__ __launch_bounds__(256) void k_permute(const int* __restrict__ etypes,
                                                 const int* __restrict__ src,
                                                 const int* __restrict__ dst,
                                                 const float* __restrict__ norm,
                                                 int* __restrict__ cursor,
                                                 int2* __restrict__ payload) {
    int e = blockIdx.x * 256 + threadIdx.x;
    if (e >= N_EDGES) return;
    int d = dst[e];
    int pos = atomicAdd(&cursor[d], 1);
    int rowid = etypes[e] * N_NODES + src[e];
    payload[pos] = make_int2(rowid, __float_as_int(norm[e]));
}

// ---------------------------------------------------------------------------
// S4: atomic-free segment sum. One wave per dst node; 4 lane-groups x 16
// lanes gather 4 tr rows (float4/lane) per iteration; shfl_xor reduce across
// groups; one coalesced 256B store per node. Writes EVERY node (zeros for
// degree-0), so no out memset needed.
// ---------------------------------------------------------------------------
__global__ __launch_bounds__(256) void k_aggregate(const float* __restrict__ tr,
                                                   const int2* __restrict__ payload,
                                                   const int* __restrict__ base,
                                                   float* __restrict__ out) {
    const int wid = (blockIdx.x * 256 + threadIdx.x) >> 6;   // dst node, wave-uniform
    const int lane = threadIdx.x & 63;
    if (wid >= N_NODES) return;
    const int g = lane >> 4, q = lane & 15;
    const int s0 = base[wid], s1 = base[wid + 1];

    float4 acc = make_float4(0.f, 0.f, 0.f, 0.f);
    for (int j = s0 + g; j < s1; j += 4) {
        int2 p = payload[j];                                  // broadcast within group
        float nv = __int_as_float(p.y);
        float4 v = *(const float4*)(tr + (size_t)p.x * OUT_FEAT + q * 4);
        acc.x += v.x * nv;
        acc.y += v.y * nv;
        acc.z += v.z * nv;
        acc.w += v.w * nv;
    }
    // reduce the 4 groups (lane^16, lane^32)
    #pragma unroll
    for (int mask = 16; mask <= 32; mask <<= 1) {
        acc.x += __shfl_xor(acc.x, mask, 64);
        acc.y += __shfl_xor(acc.y, mask, 64);
        acc.z += __shfl_xor(acc.z, mask, 64);
        acc.w += __shfl_xor(acc.w, mask, 64);
    }
    if (g == 0) *(float4*)(out + (size_t)wid * OUT_FEAT + q * 4) = acc;
}

// ---------------------------------------------------------------------------
// Fallback paths (smaller ws): round-2 atomic scatter / direct matvec.
// ---------------------------------------------------------------------------
__global__ __launch_bounds__(256) void k_scatter(const float* __restrict__ tr,
                                                 const float* __restrict__ norm,
                                                 const int* __restrict__ etypes,
                                                 const int* __restrict__ src,
                                                 const int* __restrict__ dst,
                                                 float* __restrict__ out) {
    int gid = blockIdx.x * 256 + threadIdx.x;
    int e = gid >> 4;
    int q = gid & 15;
    if (e >= N_EDGES) return;
    int et = etypes[e];
    int s  = src[e];
    int d  = dst[e];
    float nv = norm[e];
    float4 v = *(const float4*)(tr + ((size_t)et * N_NODES + s) * OUT_FEAT + q * 4);
    float* op = out + (size_t)d * OUT_FEAT + q * 4;
    atomicAdd(op + 0, v.x * nv);
    atomicAdd(op + 1, v.y * nv);
    atomicAdd(op + 2, v.z * nv);
    atomicAdd(op + 3, v.w * nv);
}

__global__ __launch_bounds__(256) void k_direct(const float* __restrict__ feat,
                                                const float* __restrict__ W,
                                                const float* __restrict__ norm,
                                                const int* __restrict__ etypes,
                                                const int* __restrict__ src,
                                                const int* __restrict__ dst,
                                                float* __restrict__ out) {
    int gid = blockIdx.x * 256 + threadIdx.x;
    int e = gid >> 4;
    int q = gid & 15;
    if (e >= N_EDGES) return;
    int et = etypes[e];
    int s  = src[e];
    int d  = dst[e];
    float nv = norm[e];
    const float* fs = feat + (size_t)s * IN_FEAT;
    const float* wp = W + (size_t)et * 4096 + q * 4;
    float ax = 0.f, ay = 0.f, az = 0.f, aw = 0.f;
    #pragma unroll 8
    for (int i = 0; i < IN_FEAT; ++i) {
        float f = fs[i];
        float4 w = *(const float4*)(wp + i * OUT_FEAT);
        ax += f * w.x; ay += f * w.y; az += f * w.z; aw += f * w.w;
    }
    float* op = out + (size_t)d * OUT_FEAT + q * 4;
    atomicAdd(op + 0, ax * nv);
    atomicAdd(op + 1, ay * nv);
    atomicAdd(op + 2, az * nv);
    atomicAdd(op + 3, aw * nv);
}

extern "C" void kernel_launch(void* const* d_in, const int* in_sizes, int n_in,
                              void* d_out, int out_size, void* d_ws, size_t ws_size,
                              hipStream_t stream) {
    const float* feat   = (const float*)d_in[0];
    const float* norm   = (const float*)d_in[1];
    const float* W      = (const float*)d_in[2];
    const int*   etypes = (const int*)d_in[3];
    const int*   src    = (const int*)d_in[4];
    const int*   dst    = (const int*)d_in[5];
    float* out = (float*)d_out;

    const int ntiles = (N_NODES + 63) / 64;           // 1563
    const int nscat  = (N_EDGES * 16) / 256;          // 100000
    const int nedgeb = (N_EDGES + 255) / 256;         // 6250

    // ws layout (all offsets 256B-aligned)
    const size_t sz_tr      = (size_t)NUM_RELS * N_NODES * OUT_FEAT * sizeof(float); // 204,800,000
    const size_t sz_count   = 100608 * sizeof(int);   // N padded
    const size_t sz_base    = 100608 * sizeof(int);   // N+1 padded
    const size_t sz_cursor  = 100608 * sizeof(int);
    const size_t sz_bsum    = 256 * sizeof(int);
    const size_t sz_boff    = 256 * sizeof(int);
    const size_t sz_payload = (size_t)N_EDGES * sizeof(int2);                        // 12,800,000

    char* p = (char*)d_ws;
    float* tr      = (float*)p;                 p += sz_tr;
    int*   count   = (int*)p;                   p += sz_count;
    int*   base    = (int*)p;                   p += sz_base;
    int*   cursor  = (int*)p;                   p += sz_cursor;
    int*   bsum    = (int*)p;                   p += sz_bsum;
    int*   boff    = (int*)p;                   p += sz_boff;
    int2*  payload = (int2*)p;                  p += sz_payload;
    const size_t need_sorted = (size_t)(p - (char*)d_ws);
    const size_t need_tr     = sz_tr;

    if (ws_size >= need_sorted) {
        hipMemsetAsync(count, 0, sz_count, stream);
        k_transform<<<ntiles, 256, 0, stream>>>(feat, W, tr);
        k_hist     <<<nedgeb, 256, 0, stream>>>(dst, count);
        k_scan_local<<<SCAN_NB, 256, 0, stream>>>(count, base, bsum);
        k_scan_blocks<<<1, 64, 0, stream>>>(bsum, boff);
        k_scan_fix <<<SCAN_NB, 256, 0, stream>>>(base, cursor, boff);
        k_permute  <<<nedgeb, 256, 0, stream>>>(etypes, src, dst, norm, cursor, payload);
        k_aggregate<<<(N_NODES * 64 + 255) / 256, 256, 0, stream>>>(tr, payload, base, out);
    } else if (ws_size >= need_tr) {
        hipMemsetAsync(d_out, 0, (size_t)out_size * sizeof(float), stream);
        k_transform<<<ntiles, 256, 0, stream>>>(feat, W, tr);
        k_scatter<<<nscat, 256, 0, stream>>>(tr, norm, etypes, src, dst, out);
    } else {
        hipMemsetAsync(d_out, 0, (size_t)out_size * sizeof(float), stream);
        k_direct<<<nscat, 256, 0, stream>>>(feat, W, norm, etypes, src, dst, out);
    }
}